// Round 2
// baseline (405.088 us; speedup 1.0000x reference)
//
#include <hip/hip_runtime.h>

#define NBINS 1331           // 11^3
#define NCUT  11
#define TOPK  20
#define HIST_BLOCKS 1024
#define HIST_THREADS 256

// ---------------- workspace layout ----------------
// ws + 0 : unsigned int ghist[1331]
#define WS_HIST_OFF   0

// Sort/clip/pin one 11-cut vector (reference _transform_cut), lane-local.
__device__ inline void transform_cut(const float* __restrict__ src, float* dst) {
    float s[NCUT];
    for (int i = 0; i < NCUT; ++i) s[i] = src[i];
    for (int i = 1; i < NCUT; ++i) {           // insertion sort ascending
        float v = s[i];
        int j = i - 1;
        while (j >= 0 && s[j] > v) { s[j + 1] = s[j]; --j; }
        s[j + 1] = v;
    }
    for (int i = 0; i < NCUT; ++i) s[i] = fminf(fmaxf(s[i], 0.0f), 1.0f);
    s[0] = 0.0f;
    s[NCUT - 1] = 1.0f;
    for (int i = 0; i < NCUT; ++i) dst[i] = s[i];
}

__global__ __launch_bounds__(HIST_THREADS) void hist_kernel(
        const float4* __restrict__ x,
        const float* __restrict__ r_cut,
        const float* __restrict__ g_cut,
        const float* __restrict__ b_cut,
        unsigned int* __restrict__ ghist,
        int npix) {
    __shared__ unsigned int sh[NBINS];
    __shared__ float scut[3 * NCUT];           // cuts * 255

    int t = threadIdx.x;
    for (int i = t; i < NBINS; i += HIST_THREADS) sh[i] = 0;
    if (t < 3) {
        const float* src = (t == 0) ? r_cut : ((t == 1) ? g_cut : b_cut);
        float s[NCUT];
        transform_cut(src, s);
        for (int i = 0; i < NCUT; ++i)
            scut[t * NCUT + i] = s[i] * 255.0f;   // same fp32 mul as JAX rc*255
    }
    __syncthreads();

    float cr[NCUT], cg[NCUT], cb[NCUT];
#pragma unroll
    for (int j = 0; j < NCUT; ++j) {
        cr[j] = scut[j];
        cg[j] = scut[NCUT + j];
        cb[j] = scut[2 * NCUT + j];
    }

    const int stride = gridDim.x * HIST_THREADS;
    int i = blockIdx.x * HIST_THREADS + t;
    for (; i < npix; i += 2 * stride) {
        float4 a = x[i];
        bool has2 = (i + stride) < npix;
        float4 b = has2 ? x[i + stride] : a;

        int r0 = 0, g0 = 0, b0 = 0, r1 = 0, g1 = 0, b1 = 0;
#pragma unroll
        for (int j = 0; j < NCUT; ++j) {
            r0 += (cr[j] < a.x); g0 += (cg[j] < a.y); b0 += (cb[j] < a.z);
            r1 += (cr[j] < b.x); g1 += (cg[j] < b.y); b1 += (cb[j] < b.z);
        }
        r0 = r0 ? (r0 - 1) : (NCUT - 1);
        g0 = g0 ? (g0 - 1) : (NCUT - 1);
        b0 = b0 ? (b0 - 1) : (NCUT - 1);
        atomicAdd(&sh[r0 * 121 + g0 * 11 + b0], 1u);
        if (has2) {
            r1 = r1 ? (r1 - 1) : (NCUT - 1);
            g1 = g1 ? (g1 - 1) : (NCUT - 1);
            b1 = b1 ? (b1 - 1) : (NCUT - 1);
            atomicAdd(&sh[r1 * 121 + g1 * 11 + b1], 1u);
        }
    }
    __syncthreads();
    for (int j = t; j < NBINS; j += HIST_THREADS) {
        unsigned int c = sh[j];
        if (c) atomicAdd(&ghist[j], c);
    }
}

// Single-wave top-20: keys in registers, butterfly shuffles, no syncthreads
// in the selection loop.
#define SLOTS 21   // ceil(1331/64)
__global__ __launch_bounds__(64) void topk_kernel(
        const unsigned int* __restrict__ ghist,
        const float* __restrict__ r_cut,
        const float* __restrict__ g_cut,
        const float* __restrict__ b_cut,
        float* __restrict__ out) {
    __shared__ float cutraw[3 * NCUT];
    int t = threadIdx.x;
    if (t < 3) {
        const float* src = (t == 0) ? r_cut : ((t == 1) ? g_cut : b_cut);
        transform_cut(src, &cutraw[t * NCUT]);
    }
    __syncthreads();

    // key: higher count wins; tie -> lower bin index wins (stable argsort(-c))
    unsigned long long k[SLOTS];
#pragma unroll
    for (int s = 0; s < SLOTS; ++s) {
        int bin = t + 64 * s;
        k[s] = (bin < NBINS)
                 ? (((unsigned long long)ghist[bin] << 11) |
                    (unsigned long long)(2047 - bin))
                 : 0ull;
    }

    int mybin = 0;
#pragma unroll 1
    for (int it = 0; it < TOPK; ++it) {
        unsigned long long m = 0ull;
#pragma unroll
        for (int s = 0; s < SLOTS; ++s) m = (k[s] > m) ? k[s] : m;
#pragma unroll
        for (int d = 1; d < 64; d <<= 1) {
            unsigned long long o = __shfl_xor(m, d);
            m = (o > m) ? o : m;
        }
        int bin = 2047 - (int)(m & 2047ull);
        if (it == t) mybin = bin;          // lane `it` records winner #it
#pragma unroll
        for (int s = 0; s < SLOTS; ++s)
            if (bin == t + 64 * s) k[s] = 0ull;   // remove winner
    }

    if (t < TOPK) {
        int bin = mybin;
        int tr = (bin / 121) % NCUT;
        int tg = (bin / 11) % NCUT;
        int tb = bin % NCUT;
        int r = min(tr, NCUT - 2);
        int g = min(tg, NCUT - 2);
        int b = min(tb, NCUT - 2);
        const float* rc = cutraw;
        const float* gc = cutraw + NCUT;
        const float* bc = cutraw + 2 * NCUT;
        float4 o;
        o.x = 255.0f * (float)r / 11.0f + (rc[r + 1] - rc[r]) * 255.0f / 2.0f;
        o.y = 255.0f * (float)g / 11.0f + (gc[g + 1] - gc[g]) * 255.0f / 2.0f;
        o.z = 255.0f * (float)b / 11.0f + (bc[b + 1] - bc[b]) * 255.0f / 2.0f;
        o.w = 255.0f;
        reinterpret_cast<float4*>(out)[t] = o;
    }
}

extern "C" void kernel_launch(void* const* d_in, const int* in_sizes, int n_in,
                              void* d_out, int out_size, void* d_ws, size_t ws_size,
                              hipStream_t stream) {
    const float* x     = (const float*)d_in[0];
    const float* r_cut = (const float*)d_in[1];
    const float* g_cut = (const float*)d_in[2];
    const float* b_cut = (const float*)d_in[3];
    float* out = (float*)d_out;

    int npix = in_sizes[0] / 4;

    unsigned int* ghist = (unsigned int*)((char*)d_ws + WS_HIST_OFF);

    // ws is poisoned 0xAA before every launch: zero the histogram each call.
    hipMemsetAsync(ghist, 0, NBINS * sizeof(unsigned int), stream);

    hist_kernel<<<HIST_BLOCKS, HIST_THREADS, 0, stream>>>(
        (const float4*)x, r_cut, g_cut, b_cut, ghist, npix);

    topk_kernel<<<1, 64, 0, stream>>>(ghist, r_cut, g_cut, b_cut, out);
}